// Round 6
// baseline (445.354 us; speedup 1.0000x reference)
//
#include <hip/hip_runtime.h>
#include <stdint.h>

#define E_TOTAL 1000000
#define N_NODES 100000
#define FD      128
#define ETILE   64
#define NTILES  (E_TOTAL / ETILE)   // 15625 exactly
#define GRID    3125                // 5 tiles per block exactly
#define KTILES  5

typedef __attribute__((ext_vector_type(8))) short short8;
typedef __attribute__((ext_vector_type(4))) float f32x4;

// round-to-nearest-even fp32 -> bf16 (bit pattern in a short)
__device__ __forceinline__ short f2bf(float f) {
  union { float f; unsigned u; } v; v.f = f;
  unsigned r = (v.u + 0x7FFFu + ((v.u >> 16) & 1u)) >> 16;
  return (short)(r & 0xFFFFu);
}

// ---- pre-pass: x fp32 -> bf16 table in workspace (8 floats / thread) ----
__global__ __launch_bounds__(256)
void convert_x_kernel(const float* __restrict__ x, short* __restrict__ xb) {
  const int i = (blockIdx.x * 256 + threadIdx.x) * 8;   // grid sized exactly
  float4 a = *(const float4*)(x + i);
  float4 b = *(const float4*)(x + i + 4);
  short8 s;
  s[0] = f2bf(a.x); s[1] = f2bf(a.y); s[2] = f2bf(a.z); s[3] = f2bf(a.w);
  s[4] = f2bf(b.x); s[5] = f2bf(b.y); s[6] = f2bf(b.z); s[7] = f2bf(b.w);
  *(short8*)(xb + i) = s;
}

template <bool USEBF>
__global__ __launch_bounds__(256, 3)   // 3 waves/EU target; est. total regs ~150 < 170 cap.
                                       // (256,2) left ~172 total -> stuck at 2 blocks/CU.
void linkpred_kernel(const float* __restrict__ x,
                     const short* __restrict__ xbf,    // bf16 x table (if USEBF)
                     const int* __restrict__ ei,       // [2][E_TOTAL], int32
                     const float* __restrict__ W1, const float* __restrict__ b1,
                     const float* __restrict__ A1,
                     const float* __restrict__ W2, const float* __restrict__ b2,
                     const float* __restrict__ A2,
                     const float* __restrict__ W3, const float* __restrict__ b3,
                     const float* __restrict__ A3,
                     const float* __restrict__ Wf, const float* __restrict__ bfp,
                     float* __restrict__ out)
{
  // No H0: layer-1 A-fragments are loaded straight from global memory.
  __shared__ __align__(16) short H1[ETILE][72];   // 9216 B
  __shared__ __align__(16) short H2[ETILE][40];   // 5120 B

  const int tid  = threadIdx.x;
  const int w    = tid >> 6;     // wave 0..3
  const int lane = tid & 63;
  const int col  = lane & 15;
  const int quad = lane >> 4;    // 0..3

  // ---------------- register-resident weight B-fragments ----------------
  short8 B1f[2][8];
  for (int p = 0; p < 2; ++p) {
    const int n = 16 * (w + 4 * p) + col;
    const float* src = (p == 0) ? (W1 + n) : (A1 + (n - 64));
    for (int kt = 0; kt < 8; ++kt) {
      short8 f;
      for (int j = 0; j < 8; ++j)
        f[j] = f2bf(src[(kt * 32 + quad * 8 + j) * 64]);
      B1f[p][kt] = f;
    }
  }
  short8 B2f[2][2];
  for (int p = 0; p < 2; ++p) {
    const int n = 16 * ((w & 1) + 2 * p) + col;
    const float* src = (p == 0) ? (W2 + n) : (A2 + (n - 32));
    for (int kt = 0; kt < 2; ++kt) {
      short8 f;
      for (int j = 0; j < 8; ++j)
        f[j] = f2bf(src[(kt * 32 + quad * 8 + j) * 32]);
      B2f[p][kt] = f;
    }
  }
  short8 B3f[2];
  for (int p = 0; p < 2; ++p) {
    const int n = 16 * p + col;
    const float* src = (p == 0) ? (W3 + n) : (A3 + (n - 16));
    short8 f;
    for (int j = 0; j < 8; ++j)
      f[j] = f2bf(src[(quad * 8 + j) * 16]);
    B3f[p] = f;
  }
  const float b1v = b1[16 * w + col];
  const float b2v = b2[16 * (w & 1) + col];
  const float b3v = b3[col];
  const float bfv = bfp[0];
  const float wfv = Wf[col];
  const f32x4 zero = {0.f, 0.f, 0.f, 0.f};

  const char* xb8    = USEBF ? (const char*)xbf : (const char*)x;
  const unsigned qo  = USEBF ? (unsigned)(quad * 16) : (unsigned)(quad * 32);
  const int      rsh = USEBF ? 8 : 9;              // row bytes: 256 (bf16) / 512 (fp32)
  const int      col4 = col * 4;                   // bpermute byte-lane base

  int tile = blockIdx.x;
  for (int k = 0; k < KTILES; ++k, tile += GRID) {
    const int e0 = tile * ETILE;

    // ---- per-lane edge indices (coalesced) + per-mt row offsets via bpermute ----
    const int vs = ei[e0 + lane];                  // edge (e0+lane) src
    const int vd = ei[E_TOTAL + e0 + lane];        // edge (e0+lane) dst
    unsigned voff[8];                              // [mt]=src row, [4+mt]=dst row
#pragma unroll
    for (int mt = 0; mt < 4; ++mt) {
      const int tl = mt * 64 + col4;               // target lane (mt*16+col) * 4 bytes
      const int ns = __builtin_amdgcn_ds_bpermute(tl, vs);
      const int nd = __builtin_amdgcn_ds_bpermute(tl, vd);
      voff[mt]     = ((unsigned)ns << rsh) + qo;
      voff[4 + mt] = ((unsigned)nd << rsh) + qo;
    }

    // A-fragment loader: lane (col,quad), edge row (mt*16+col), K-tile kt of the
    // [x_src | x_dst] concat. kt<4 -> src row bytes [kt*64+quad*16); kt>=4 -> dst.
    auto lfrag = [&](int mtg, int kt) -> short8 {
      const char* p = xb8 + ((kt < 4) ? voff[mtg] : voff[4 + mtg]);
      if constexpr (USEBF) {
        return *(const short8*)(p + (kt & 3) * 64);
      } else {
        float4 f0 = *(const float4*)(p + (kt & 3) * 128);
        float4 f1 = *(const float4*)(p + (kt & 3) * 128 + 16);
        short8 s;
        s[0] = f2bf(f0.x); s[1] = f2bf(f0.y); s[2] = f2bf(f0.z); s[3] = f2bf(f0.w);
        s[4] = f2bf(f1.x); s[5] = f2bf(f1.y); s[6] = f2bf(f1.z); s[7] = f2bf(f1.w);
        return s;
      }
    };

    // ---- layer 1: [64x256] @ [256x128]; wave w -> cols {16w, 64+16w}; two M-passes
    //      (acc 16 regs/pass; 1-kt load lookahead keeps <=4 dwordx4 in flight) ----
#pragma unroll
    for (int p2 = 0; p2 < 2; ++p2) {
      f32x4 accW[2], accA[2];
      accW[0] = zero; accW[1] = zero; accA[0] = zero; accA[1] = zero;
      short8 a0 = lfrag(2 * p2, 0), a1 = lfrag(2 * p2 + 1, 0);
#pragma unroll
      for (int kt = 0; kt < 8; ++kt) {
        short8 n0, n1;
        if (kt < 7) { n0 = lfrag(2 * p2, kt + 1); n1 = lfrag(2 * p2 + 1, kt + 1); }
        accW[0] = __builtin_amdgcn_mfma_f32_16x16x32_bf16(a0, B1f[0][kt], accW[0], 0, 0, 0);
        accA[0] = __builtin_amdgcn_mfma_f32_16x16x32_bf16(a0, B1f[1][kt], accA[0], 0, 0, 0);
        accW[1] = __builtin_amdgcn_mfma_f32_16x16x32_bf16(a1, B1f[0][kt], accW[1], 0, 0, 0);
        accA[1] = __builtin_amdgcn_mfma_f32_16x16x32_bf16(a1, B1f[1][kt], accA[1], 0, 0, 0);
        a0 = n0; a1 = n1;
      }
      for (int mi = 0; mi < 2; ++mi)
        for (int r = 0; r < 4; ++r) {
          float o = fmaxf(accW[mi][r] + b1v, 0.f);      // relu(h@W1 + b1)
          float h = fmaxf(o + accA[mi][r], 0.f);        // relu(out + h@A1)
          H1[(2 * p2 + mi) * 16 + quad * 4 + r][16 * w + col] = f2bf(h);
        }
    }
    __syncthreads();   // barrier 1: H1 complete (also orders H2(k-1) reads vs writes below)

    // ---- layer 2: [64x64] @ [64x64], waves split M in halves ----
    f32x4 acc2[2][2];
    acc2[0][0] = zero; acc2[0][1] = zero; acc2[1][0] = zero; acc2[1][1] = zero;
    for (int kt = 0; kt < 2; ++kt)
      for (int mi = 0; mi < 2; ++mi) {
        const int m = (2 * (w >> 1) + mi) * 16 + col;
        short8 a = *(const short8*)&H1[m][kt * 32 + quad * 8];
        acc2[mi][0] = __builtin_amdgcn_mfma_f32_16x16x32_bf16(a, B2f[0][kt], acc2[mi][0], 0, 0, 0);
        acc2[mi][1] = __builtin_amdgcn_mfma_f32_16x16x32_bf16(a, B2f[1][kt], acc2[mi][1], 0, 0, 0);
      }
    for (int mi = 0; mi < 2; ++mi)
      for (int r = 0; r < 4; ++r) {
        float o = fmaxf(acc2[mi][0][r] + b2v, 0.f);
        float h = fmaxf(o + acc2[mi][1][r], 0.f);
        H2[(2 * (w >> 1) + mi) * 16 + quad * 4 + r][16 * (w & 1) + col] = f2bf(h);
      }
    __syncthreads();   // barrier 2: H2 complete (also orders H1(k) reads vs H1(k+1) writes)

    // ---- layer 3: [64x32] @ [32x32], wave w -> M-tile w ----
    f32x4 acc3[2];
    acc3[0] = zero; acc3[1] = zero;
    {
      short8 a = *(const short8*)&H2[w * 16 + col][quad * 8];
      acc3[0] = __builtin_amdgcn_mfma_f32_16x16x32_bf16(a, B3f[0], acc3[0], 0, 0, 0);
      acc3[1] = __builtin_amdgcn_mfma_f32_16x16x32_bf16(a, B3f[1], acc3[1], 0, 0, 0);
    }

    // ---- final 16-dot via shuffle butterfly + sigmoid, packed float4 store ----
    float4 res;
    float* resp = (float*)&res;
    for (int r = 0; r < 4; ++r) {
      float o = fmaxf(acc3[0][r] + b3v, 0.f);
      float h = fmaxf(o + acc3[1][r], 0.f);
      float s = h * wfv;
      s += __shfl_xor(s, 1, 16);
      s += __shfl_xor(s, 2, 16);
      s += __shfl_xor(s, 4, 16);
      s += __shfl_xor(s, 8, 16);
      resp[r] = 1.0f / (1.0f + __expf(-(s + bfv)));
    }
    if (col == 0)
      *(float4*)(out + e0 + w * 16 + quad * 4) = res;
    // no tail barrier: H1(k+1) writes are after barrier-2(k); H2(k+1) writes after
    // barrier-1(k+1); all readers of H1(k)/H2(k) retire before those barriers.
  }
}

extern "C" void kernel_launch(void* const* d_in, const int* in_sizes, int n_in,
                              void* d_out, int out_size, void* d_ws, size_t ws_size,
                              hipStream_t stream) {
  const float* x   = (const float*)d_in[0];
  const int*   ei  = (const int*)d_in[1];
  const float* W1  = (const float*)d_in[2];
  const float* b1  = (const float*)d_in[3];
  const float* A1  = (const float*)d_in[4];
  const float* W2  = (const float*)d_in[5];
  const float* b2  = (const float*)d_in[6];
  const float* A2  = (const float*)d_in[7];
  const float* W3  = (const float*)d_in[8];
  const float* b3  = (const float*)d_in[9];
  const float* A3  = (const float*)d_in[10];
  const float* Wf  = (const float*)d_in[11];
  const float* bfp = (const float*)d_in[12];

  const size_t xb_bytes = (size_t)N_NODES * FD * sizeof(short);  // 25.6 MB

  if (ws_size >= xb_bytes) {
    short* xb = (short*)d_ws;
    hipLaunchKernelGGL(convert_x_kernel, dim3(N_NODES * FD / (256 * 8)), dim3(256), 0, stream,
                       x, xb);
    hipLaunchKernelGGL((linkpred_kernel<true>), dim3(GRID), dim3(256), 0, stream,
                       x, (const short*)xb, ei, W1, b1, A1, W2, b2, A2, W3, b3, A3, Wf, bfp,
                       (float*)d_out);
  } else {
    hipLaunchKernelGGL((linkpred_kernel<false>), dim3(GRID), dim3(256), 0, stream,
                       x, (const short*)nullptr, ei, W1, b1, A1, W2, b2, A2, W3, b3, A3, Wf, bfp,
                       (float*)d_out);
  }
}